// Round 1
// baseline (255.234 us; speedup 1.0000x reference)
//
#include <hip/hip_runtime.h>

#define HD 128      // hidden width
#define NC 18       // jet coefficients
#define LSTR 20     // LDS stride (16B aligned, floats)

// Monomial index map (exponents of a=dx, b=dy, c=dt):
// 0:1 1:a 2:b 3:c 4:a2 5:ab 6:b2 7:ca 8:cb 9:a3 10:a2b 11:ab2 12:b3
// 13:ca2 14:cb2 15:a4 16:a2b2 17:b4
// Coefficients are Taylor coefficients: coef[m] = partial / (i! j! k!)

__device__ __forceinline__ void jmul(const float* __restrict__ p,
                                     const float* __restrict__ q,
                                     float* __restrict__ r) {
    r[0]  = p[0]*q[0];
    r[1]  = p[0]*q[1]  + p[1]*q[0];
    r[2]  = p[0]*q[2]  + p[2]*q[0];
    r[3]  = p[0]*q[3]  + p[3]*q[0];
    r[4]  = p[0]*q[4]  + p[4]*q[0]  + p[1]*q[1];
    r[5]  = p[0]*q[5]  + p[5]*q[0]  + p[1]*q[2]  + p[2]*q[1];
    r[6]  = p[0]*q[6]  + p[6]*q[0]  + p[2]*q[2];
    r[7]  = p[0]*q[7]  + p[7]*q[0]  + p[1]*q[3]  + p[3]*q[1];
    r[8]  = p[0]*q[8]  + p[8]*q[0]  + p[2]*q[3]  + p[3]*q[2];
    r[9]  = p[0]*q[9]  + p[9]*q[0]  + p[1]*q[4]  + p[4]*q[1];
    r[10] = p[0]*q[10] + p[10]*q[0] + p[1]*q[5]  + p[5]*q[1] + p[2]*q[4] + p[4]*q[2];
    r[11] = p[0]*q[11] + p[11]*q[0] + p[1]*q[6]  + p[6]*q[1] + p[2]*q[5] + p[5]*q[2];
    r[12] = p[0]*q[12] + p[12]*q[0] + p[2]*q[6]  + p[6]*q[2];
    r[13] = p[0]*q[13] + p[13]*q[0] + p[1]*q[7]  + p[7]*q[1] + p[3]*q[4] + p[4]*q[3];
    r[14] = p[0]*q[14] + p[14]*q[0] + p[2]*q[8]  + p[8]*q[2] + p[3]*q[6] + p[6]*q[3];
    r[15] = p[0]*q[15] + p[15]*q[0] + p[1]*q[9]  + p[9]*q[1] + p[4]*q[4];
    r[16] = p[0]*q[16] + p[16]*q[0] + p[1]*q[11] + p[11]*q[1] + p[2]*q[10] + p[10]*q[2]
          + p[4]*q[6]  + p[6]*q[4]  + p[5]*q[5];
    r[17] = p[0]*q[17] + p[17]*q[0] + p[2]*q[12] + p[12]*q[2] + p[6]*q[6];
}

// out = tanh(f) as a truncated jet.  tanh Taylor coeffs at f0:
// t0=y, t1=s, t2=-y*s, t3=s*(y^2-1/3), t4=y*s*(2-3y^2)/3,  s=1-y^2
__device__ __forceinline__ void tanh_jet(const float* __restrict__ f,
                                         float* __restrict__ out) {
    const float y  = tanhf(f[0]);
    const float s  = 1.0f - y*y;
    const float t2 = -y*s;
    const float t3 = s*(y*y - 0.3333333333333333f);
    const float t4 = y*s*(2.0f - 3.0f*y*y) * 0.3333333333333333f;
    float p[NC], A[NC], B[NC];
    p[0] = 0.0f;
#pragma unroll
    for (int i = 1; i < NC; ++i) p[i] = f[i];
    // Horner: out = y + p*(s + p*(t2 + p*(t3 + p*t4)))
    A[0] = t3;
#pragma unroll
    for (int i = 1; i < NC; ++i) A[i] = t4 * p[i];
    jmul(p, A, B);  B[0] += t2;
    jmul(p, B, A);  A[0] += s;
    jmul(p, A, out); out[0] += y;
}

__global__ __launch_bounds__(256)
void hydro_kernel(const float* __restrict__ x,
                  const float* __restrict__ W1, const float* __restrict__ b1,
                  const float* __restrict__ W2, const float* __restrict__ b2,
                  const float* __restrict__ W3, const float* __restrict__ b3,
                  const float* __restrict__ W4,
                  const float* __restrict__ nu_p,
                  float* __restrict__ out, int N) {
    __shared__ __align__(16) float hs[4][HD][LSTR];
    const int wv = threadIdx.x >> 6;
    const int ln = threadIdx.x & 63;
    const int i  = (blockIdx.x << 2) + wv;

    const float xs = x[3*i+0];
    const float ys = x[3*i+1];
    const float ts = x[3*i+2];
    const float nu = nu_p[0];

    float hA[NC], hB[NC], f[NC];
    float* hp = &hs[wv][0][0];

    // ---- Layer 1: jet is linear in (a,b,c) ----
    {
        int j = ln;
        float wx = W1[j], wy = W1[HD + j], wt = W1[2*HD + j];
#pragma unroll
        for (int c2 = 0; c2 < NC; ++c2) f[c2] = 0.0f;
        f[0] = fmaf(wx, xs, fmaf(wy, ys, fmaf(wt, ts, b1[j])));
        f[1] = wx; f[2] = wy; f[3] = wt;
        tanh_jet(f, hA);

        j = ln + 64;
        wx = W1[j]; wy = W1[HD + j]; wt = W1[2*HD + j];
#pragma unroll
        for (int c2 = 0; c2 < NC; ++c2) f[c2] = 0.0f;
        f[0] = fmaf(wx, xs, fmaf(wy, ys, fmaf(wt, ts, b1[j])));
        f[1] = wx; f[2] = wy; f[3] = wt;
        tanh_jet(f, hB);
    }
#pragma unroll
    for (int c2 = 0; c2 < NC; ++c2) hp[ln*LSTR + c2] = hA[c2];
#pragma unroll
    for (int c2 = 0; c2 < NC; ++c2) hp[(ln+64)*LSTR + c2] = hB[c2];
    __syncthreads();

    // ---- Layers 2,3: jet matvec from LDS + tanh jet ----
    const float* Wm[2] = {W2, W3};
    const float* bm[2] = {b2, b3};
#pragma unroll 1
    for (int L = 0; L < 2; ++L) {
        const float* __restrict__ W = Wm[L];
        float acc0[NC], acc1[NC];
#pragma unroll
        for (int c2 = 0; c2 < NC; ++c2) { acc0[c2] = 0.0f; acc1[c2] = 0.0f; }
        const float* Wc = W + ln;
#pragma unroll 2
        for (int k = 0; k < HD; ++k) {
            const float w0 = Wc[k*HD];
            const float w1 = Wc[k*HD + 64];
            const float* hk = hp + k*LSTR;
            const float4 u0 = *(const float4*)(hk);
            const float4 u1 = *(const float4*)(hk + 4);
            const float4 u2 = *(const float4*)(hk + 8);
            const float4 u3 = *(const float4*)(hk + 12);
            const float2 u4 = *(const float2*)(hk + 16);
            const float t[NC] = {u0.x,u0.y,u0.z,u0.w, u1.x,u1.y,u1.z,u1.w,
                                 u2.x,u2.y,u2.z,u2.w, u3.x,u3.y,u3.z,u3.w,
                                 u4.x,u4.y};
#pragma unroll
            for (int c2 = 0; c2 < NC; ++c2) {
                acc0[c2] = fmaf(w0, t[c2], acc0[c2]);
                acc1[c2] = fmaf(w1, t[c2], acc1[c2]);
            }
        }
        acc0[0] += bm[L][ln];
        acc1[0] += bm[L][ln + 64];
        tanh_jet(acc0, hA);
        tanh_jet(acc1, hB);
        if (L == 0) {
            __syncthreads();
#pragma unroll
            for (int c2 = 0; c2 < NC; ++c2) hp[ln*LSTR + c2] = hA[c2];
#pragma unroll
            for (int c2 = 0; c2 < NC; ++c2) hp[(ln+64)*LSTR + c2] = hB[c2];
            __syncthreads();
        }
    }

    // ---- Layer 4: psi jet = sum_j W4[j] * h3[j]; reduce needed coeffs ----
    const float w4a = W4[ln], w4b = W4[ln + 64];
    const int idx[11] = {1, 2, 9, 10, 11, 12, 13, 14, 15, 16, 17};
    float red[11];
#pragma unroll
    for (int c2 = 0; c2 < 11; ++c2)
        red[c2] = fmaf(w4a, hA[idx[c2]], w4b * hB[idx[c2]]);
#pragma unroll
    for (int c2 = 0; c2 < 11; ++c2) {
#pragma unroll
        for (int off = 32; off > 0; off >>= 1)
            red[c2] += __shfl_xor(red[c2], off, 64);
    }

    if (ln == 0) {
        const float psi_x  = red[0];          // coef a
        const float psi_y  = red[1];          // coef b
        const float u  = psi_y;
        const float v  = -psi_x;
        // w = -(psi_xx + psi_yy)
        const float wx = -(6.0f*red[2] + 2.0f*red[4]);            // -(psi_xxx + psi_xyy)
        const float wy = -(2.0f*red[3] + 6.0f*red[5]);            // -(psi_xxy + psi_yyy)
        const float wt = -(2.0f*red[6] + 2.0f*red[7]);            // -(psi_xxt + psi_yyt)
        const float lapw = -(24.0f*red[8] + 8.0f*red[9] + 24.0f*red[10]);
        const float nse = wt + wx*u + wy*v - nu*lapw;
        out[2*i]     = u;
        out[2*i + 1] = v;
        out[2*N + i] = nse;
    }
}

extern "C" void kernel_launch(void* const* d_in, const int* in_sizes, int n_in,
                              void* d_out, int out_size, void* d_ws, size_t ws_size,
                              hipStream_t stream) {
    const float* x  = (const float*)d_in[0];
    const float* W1 = (const float*)d_in[1];
    const float* b1 = (const float*)d_in[2];
    const float* W2 = (const float*)d_in[3];
    const float* b2 = (const float*)d_in[4];
    const float* W3 = (const float*)d_in[5];
    const float* b3 = (const float*)d_in[6];
    const float* W4 = (const float*)d_in[7];
    const float* nu = (const float*)d_in[9];
    float* out = (float*)d_out;
    const int N = in_sizes[0] / 3;   // 8192
    dim3 grid(N / 4), block(256);
    hipLaunchKernelGGL(hydro_kernel, grid, block, 0, stream,
                       x, W1, b1, W2, b2, W3, b3, W4, nu, out, N);
}

// Round 2
// 239.899 us; speedup vs baseline: 1.0639x; 1.0639x over previous
//
#include <hip/hip_runtime.h>

#define HD 128      // hidden width
#define NC 18       // jet coefficients
#define RSTR 24     // LDS row stride in bf16 elements (48 B, 16B-aligned)

typedef float f2 __attribute__((ext_vector_type(2)));

// Monomial index map (exponents of a=dx, b=dy, c=dt):
// 0:1 1:a 2:b 3:c 4:a2 5:ab 6:b2 7:ca 8:cb 9:a3 10:a2b 11:ab2 12:b3
// 13:ca2 14:cb2 15:a4 16:a2b2 17:b4

__device__ __forceinline__ unsigned pack_bf16_rne(float x, float y) {
    unsigned ux = __float_as_uint(x), uy = __float_as_uint(y);
    ux += 0x7fffu + ((ux >> 16) & 1u);
    uy += 0x7fffu + ((uy >> 16) & 1u);
    return (ux >> 16) | (uy & 0xffff0000u);
}

__device__ __forceinline__ f2 unpk(unsigned r) {
    f2 v;
    v.x = __uint_as_float(r << 16);
    v.y = __uint_as_float(r & 0xffff0000u);
    return v;
}

__device__ __forceinline__ void jmul(const float* __restrict__ p,
                                     const float* __restrict__ q,
                                     float* __restrict__ r) {
    r[0]  = p[0]*q[0];
    r[1]  = p[0]*q[1]  + p[1]*q[0];
    r[2]  = p[0]*q[2]  + p[2]*q[0];
    r[3]  = p[0]*q[3]  + p[3]*q[0];
    r[4]  = p[0]*q[4]  + p[4]*q[0]  + p[1]*q[1];
    r[5]  = p[0]*q[5]  + p[5]*q[0]  + p[1]*q[2]  + p[2]*q[1];
    r[6]  = p[0]*q[6]  + p[6]*q[0]  + p[2]*q[2];
    r[7]  = p[0]*q[7]  + p[7]*q[0]  + p[1]*q[3]  + p[3]*q[1];
    r[8]  = p[0]*q[8]  + p[8]*q[0]  + p[2]*q[3]  + p[3]*q[2];
    r[9]  = p[0]*q[9]  + p[9]*q[0]  + p[1]*q[4]  + p[4]*q[1];
    r[10] = p[0]*q[10] + p[10]*q[0] + p[1]*q[5]  + p[5]*q[1] + p[2]*q[4] + p[4]*q[2];
    r[11] = p[0]*q[11] + p[11]*q[0] + p[1]*q[6]  + p[6]*q[1] + p[2]*q[5] + p[5]*q[2];
    r[12] = p[0]*q[12] + p[12]*q[0] + p[2]*q[6]  + p[6]*q[2];
    r[13] = p[0]*q[13] + p[13]*q[0] + p[1]*q[7]  + p[7]*q[1] + p[3]*q[4] + p[4]*q[3];
    r[14] = p[0]*q[14] + p[14]*q[0] + p[2]*q[8]  + p[8]*q[2] + p[3]*q[6] + p[6]*q[3];
    r[15] = p[0]*q[15] + p[15]*q[0] + p[1]*q[9]  + p[9]*q[1] + p[4]*q[4];
    r[16] = p[0]*q[16] + p[16]*q[0] + p[1]*q[11] + p[11]*q[1] + p[2]*q[10] + p[10]*q[2]
          + p[4]*q[6]  + p[6]*q[4]  + p[5]*q[5];
    r[17] = p[0]*q[17] + p[17]*q[0] + p[2]*q[12] + p[12]*q[2] + p[6]*q[6];
}

// out = tanh(f) as a truncated jet (degree-4 Taylor of tanh around f[0])
__device__ __forceinline__ void tanh_jet(const float* __restrict__ f,
                                         float* __restrict__ out) {
    const float y  = tanhf(f[0]);
    const float s  = 1.0f - y*y;
    const float t2 = -y*s;
    const float t3 = s*(y*y - 0.3333333333333333f);
    const float t4 = y*s*(2.0f - 3.0f*y*y) * 0.3333333333333333f;
    float p[NC], A[NC], B[NC];
    p[0] = 0.0f;
#pragma unroll
    for (int i = 1; i < NC; ++i) p[i] = f[i];
    A[0] = t3;
#pragma unroll
    for (int i = 1; i < NC; ++i) A[i] = t4 * p[i];
    jmul(p, A, B);  B[0] += t2;
    jmul(p, B, A);  A[0] += s;
    jmul(p, A, out); out[0] += y;
}

__device__ __forceinline__ void store_jet(unsigned short* __restrict__ hp,
                                          int row, const float* __restrict__ h) {
    unsigned* r = (unsigned*)(hp + row * RSTR);
#pragma unroll
    for (int c = 0; c < 9; ++c) r[c] = pack_bf16_rne(h[2*c], h[2*c+1]);
}

__global__ __launch_bounds__(256)
void hydro_kernel(const float* __restrict__ x,
                  const float* __restrict__ W1, const float* __restrict__ b1,
                  const float* __restrict__ W2, const float* __restrict__ b2,
                  const float* __restrict__ W3, const float* __restrict__ b3,
                  const float* __restrict__ W4,
                  const float* __restrict__ nu_p,
                  float* __restrict__ out, int N) {
    // wave-private bf16 jet buffer: no __syncthreads needed anywhere
    __shared__ __align__(16) unsigned short hsb[4][HD][RSTR];
    const int wv = threadIdx.x >> 6;
    const int ln = threadIdx.x & 63;
    const int i  = (blockIdx.x << 2) + wv;

    const float xs = x[3*i+0];
    const float ys = x[3*i+1];
    const float ts = x[3*i+2];
    const float nu = nu_p[0];

    float hA[NC], hB[NC], f[NC];
    unsigned short* hp = &hsb[wv][0][0];

    // ---- Layer 1: jet is linear in (a,b,c) ----
    {
        int j = ln;
        float wx = W1[j], wy = W1[HD + j], wt = W1[2*HD + j];
#pragma unroll
        for (int c2 = 0; c2 < NC; ++c2) f[c2] = 0.0f;
        f[0] = fmaf(wx, xs, fmaf(wy, ys, fmaf(wt, ts, b1[j])));
        f[1] = wx; f[2] = wy; f[3] = wt;
        tanh_jet(f, hA);

        j = ln + 64;
        wx = W1[j]; wy = W1[HD + j]; wt = W1[2*HD + j];
#pragma unroll
        for (int c2 = 0; c2 < NC; ++c2) f[c2] = 0.0f;
        f[0] = fmaf(wx, xs, fmaf(wy, ys, fmaf(wt, ts, b1[j])));
        f[1] = wx; f[2] = wy; f[3] = wt;
        tanh_jet(f, hB);
    }
    store_jet(hp, ln,      hA);
    store_jet(hp, ln + 64, hB);

    // ---- Layers 2,3: packed-fp32 jet matvec from bf16 LDS + tanh jet ----
    const float* Wm[2] = {W2, W3};
    const float* bm[2] = {b2, b3};
#pragma unroll 1
    for (int L = 0; L < 2; ++L) {
        const float* __restrict__ Wc = Wm[L] + ln;
        f2 acc0[9], acc1[9];
#pragma unroll
        for (int p = 0; p < 9; ++p) { acc0[p] = (f2)0.0f; acc1[p] = (f2)0.0f; }
#pragma unroll 2
        for (int k = 0; k < HD; ++k) {
            const float w0 = Wc[k*HD];
            const float w1 = Wc[k*HD + 64];
            const uint4    q0 = *(const uint4*)(hp + k*RSTR);
            const uint4    q1 = *(const uint4*)(hp + k*RSTR + 8);
            const unsigned q2 = *(const unsigned*)(hp + k*RSTR + 16);
            f2 t[9];
            t[0] = unpk(q0.x); t[1] = unpk(q0.y); t[2] = unpk(q0.z); t[3] = unpk(q0.w);
            t[4] = unpk(q1.x); t[5] = unpk(q1.y); t[6] = unpk(q1.z); t[7] = unpk(q1.w);
            t[8] = unpk(q2);
            const f2 w00 = {w0, w0};
            const f2 w11 = {w1, w1};
#pragma unroll
            for (int p = 0; p < 9; ++p) {
                acc0[p] = acc0[p] + w00 * t[p];   // -> v_pk_fma_f32
                acc1[p] = acc1[p] + w11 * t[p];
            }
        }
        float fa[NC], fb[NC];
#pragma unroll
        for (int p = 0; p < 9; ++p) {
            fa[2*p] = acc0[p].x; fa[2*p+1] = acc0[p].y;
            fb[2*p] = acc1[p].x; fb[2*p+1] = acc1[p].y;
        }
        fa[0] += bm[L][ln];
        fb[0] += bm[L][ln + 64];
        tanh_jet(fa, hA);
        tanh_jet(fb, hB);
        if (L == 0) {
            store_jet(hp, ln,      hA);
            store_jet(hp, ln + 64, hB);
        }
    }

    // ---- Layer 4: psi jet = sum_j W4[j] * h3[j]; reduce needed coeffs ----
    const float w4a = W4[ln], w4b = W4[ln + 64];
    const int idx[11] = {1, 2, 9, 10, 11, 12, 13, 14, 15, 16, 17};
    float red[11];
#pragma unroll
    for (int c2 = 0; c2 < 11; ++c2)
        red[c2] = fmaf(w4a, hA[idx[c2]], w4b * hB[idx[c2]]);
#pragma unroll
    for (int c2 = 0; c2 < 11; ++c2) {
#pragma unroll
        for (int off = 32; off > 0; off >>= 1)
            red[c2] += __shfl_xor(red[c2], off, 64);
    }

    if (ln == 0) {
        const float psi_x  = red[0];          // coef a
        const float psi_y  = red[1];          // coef b
        const float u  = psi_y;
        const float v  = -psi_x;
        const float wx = -(6.0f*red[2] + 2.0f*red[4]);   // w_x
        const float wy = -(2.0f*red[3] + 6.0f*red[5]);   // w_y
        const float wt = -(2.0f*red[6] + 2.0f*red[7]);   // w_t
        const float lapw = -(24.0f*red[8] + 8.0f*red[9] + 24.0f*red[10]);
        const float nse = wt + wx*u + wy*v - nu*lapw;
        out[2*i]     = u;
        out[2*i + 1] = v;
        out[2*N + i] = nse;
    }
}

extern "C" void kernel_launch(void* const* d_in, const int* in_sizes, int n_in,
                              void* d_out, int out_size, void* d_ws, size_t ws_size,
                              hipStream_t stream) {
    const float* x  = (const float*)d_in[0];
    const float* W1 = (const float*)d_in[1];
    const float* b1 = (const float*)d_in[2];
    const float* W2 = (const float*)d_in[3];
    const float* b2 = (const float*)d_in[4];
    const float* W3 = (const float*)d_in[5];
    const float* b3 = (const float*)d_in[6];
    const float* W4 = (const float*)d_in[7];
    const float* nu = (const float*)d_in[9];
    float* out = (float*)d_out;
    const int N = in_sizes[0] / 3;   // 8192
    dim3 grid(N / 4), block(256);
    hipLaunchKernelGGL(hydro_kernel, grid, block, 0, stream,
                       x, W1, b1, W2, b2, W3, b3, W4, nu, out, N);
}

// Round 3
// 106.722 us; speedup vs baseline: 2.3916x; 2.2479x over previous
//
#include <hip/hip_runtime.h>

#define NSAMP 8192
#define HD 128
#define NC 18
#define SB 8            // samples per block
#define NCOLS 144       // SB*NC
#define KSTR 136        // padded k-stride (272B rows, 16B-aligned)

typedef __attribute__((ext_vector_type(8))) short bf16x8;
typedef __attribute__((ext_vector_type(4))) float f32x4;
typedef float f2 __attribute__((ext_vector_type(2)));

// Monomial map: 0:1 1:a 2:b 3:c 4:a2 5:ab 6:b2 7:ca 8:cb 9:a3 10:a2b 11:ab2
// 12:b3 13:ca2 14:cb2 15:a4 16:a2b2 17:b4   (a=dx, b=dy, c=dt)

__device__ __forceinline__ unsigned pack_bf16_rne(float x, float y) {
    unsigned ux = __float_as_uint(x), uy = __float_as_uint(y);
    ux += 0x7fffu + ((ux >> 16) & 1u);
    uy += 0x7fffu + ((uy >> 16) & 1u);
    return (ux >> 16) | (uy & 0xffff0000u);
}
__device__ __forceinline__ float bf_lo(unsigned r) { return __uint_as_float(r << 16); }
__device__ __forceinline__ float bf_hi(unsigned r) { return __uint_as_float(r & 0xffff0000u); }

__device__ __forceinline__ void jmul(const float* __restrict__ p,
                                     const float* __restrict__ q,
                                     float* __restrict__ r) {
    r[0]  = p[0]*q[0];
    r[1]  = p[0]*q[1]  + p[1]*q[0];
    r[2]  = p[0]*q[2]  + p[2]*q[0];
    r[3]  = p[0]*q[3]  + p[3]*q[0];
    r[4]  = p[0]*q[4]  + p[4]*q[0]  + p[1]*q[1];
    r[5]  = p[0]*q[5]  + p[5]*q[0]  + p[1]*q[2]  + p[2]*q[1];
    r[6]  = p[0]*q[6]  + p[6]*q[0]  + p[2]*q[2];
    r[7]  = p[0]*q[7]  + p[7]*q[0]  + p[1]*q[3]  + p[3]*q[1];
    r[8]  = p[0]*q[8]  + p[8]*q[0]  + p[2]*q[3]  + p[3]*q[2];
    r[9]  = p[0]*q[9]  + p[9]*q[0]  + p[1]*q[4]  + p[4]*q[1];
    r[10] = p[0]*q[10] + p[10]*q[0] + p[1]*q[5]  + p[5]*q[1] + p[2]*q[4] + p[4]*q[2];
    r[11] = p[0]*q[11] + p[11]*q[0] + p[1]*q[6]  + p[6]*q[1] + p[2]*q[5] + p[5]*q[2];
    r[12] = p[0]*q[12] + p[12]*q[0] + p[2]*q[6]  + p[6]*q[2];
    r[13] = p[0]*q[13] + p[13]*q[0] + p[1]*q[7]  + p[7]*q[1] + p[3]*q[4] + p[4]*q[3];
    r[14] = p[0]*q[14] + p[14]*q[0] + p[2]*q[8]  + p[8]*q[2] + p[3]*q[6] + p[6]*q[3];
    r[15] = p[0]*q[15] + p[15]*q[0] + p[1]*q[9]  + p[9]*q[1] + p[4]*q[4];
    r[16] = p[0]*q[16] + p[16]*q[0] + p[1]*q[11] + p[11]*q[1] + p[2]*q[10] + p[10]*q[2]
          + p[4]*q[6]  + p[6]*q[4]  + p[5]*q[5];
    r[17] = p[0]*q[17] + p[17]*q[0] + p[2]*q[12] + p[12]*q[2] + p[6]*q[6];
}

__device__ __forceinline__ void tanh_jet(const float* __restrict__ f,
                                         float* __restrict__ out) {
    const float y  = tanhf(f[0]);
    const float s  = 1.0f - y*y;
    const float t2 = -y*s;
    const float t3 = s*(y*y - 0.3333333333333333f);
    const float t4 = y*s*(2.0f - 3.0f*y*y) * 0.3333333333333333f;
    float p[NC], A[NC], B[NC];
    p[0] = 0.0f;
#pragma unroll
    for (int i = 1; i < NC; ++i) p[i] = f[i];
    A[0] = t3;
#pragma unroll
    for (int i = 1; i < NC; ++i) A[i] = t4 * p[i];
    jmul(p, A, B);  B[0] += t2;
    jmul(p, B, A);  A[0] += s;
    jmul(p, A, out); out[0] += y;
}

// ---- pre-kernel: W2,W3 fp32 [k][j] -> bf16 W^T [j][k] padded (KSTR) in ws ----
__global__ __launch_bounds__(256)
void transpose_w(const float* __restrict__ W2, const float* __restrict__ W3,
                 unsigned* __restrict__ wsT) {
    const int id = blockIdx.x * 256 + threadIdx.x;
    if (id >= 2 * HD * (KSTR / 2)) return;
    const int L  = id / (HD * (KSTR / 2));
    const int r  = id % (HD * (KSTR / 2));
    const int j  = r / (KSTR / 2);
    const int kp = r % (KSTR / 2);
    const int k0 = 2 * kp, k1 = 2 * kp + 1;
    const float* W = L ? W3 : W2;
    const float f0 = (k0 < HD) ? W[k0 * HD + j] : 0.0f;
    const float f1 = (k1 < HD) ? W[k1 * HD + j] : 0.0f;
    wsT[L * (HD * (KSTR / 2)) + j * (KSTR / 2) + kp] = pack_bf16_rne(f0, f1);
}

__global__ __launch_bounds__(512, 4)
void hydro_main(const float* __restrict__ x,
                const float* __restrict__ W1, const float* __restrict__ b1,
                const float* __restrict__ b2, const float* __restrict__ b3,
                const float* __restrict__ W4, const float* __restrict__ nu_p,
                const unsigned short* __restrict__ wsT,
                float* __restrict__ out) {
    __shared__ __align__(16) unsigned short Hl[NCOLS * KSTR];  // jets/preacts, bf16
    __shared__ float psis[NCOLS];

    const int tid = threadIdx.x;
    const int wv  = tid >> 6;
    const int ln  = tid & 63;
    const int s0  = blockIdx.x * SB;

    // ---- Layer 1: 512 units (s, j-pair) ----
    {
        const int s  = tid >> 6;          // 0..7
        const int jp = tid & 63;
        const float xs = x[3 * (s0 + s) + 0];
        const float ys = x[3 * (s0 + s) + 1];
        const float ts = x[3 * (s0 + s) + 2];
        float ha[NC], hb[NC], f[NC];
#pragma unroll
        for (int c = 0; c < NC; ++c) f[c] = 0.0f;
        int j = 2 * jp;
        float wx = W1[j], wy = W1[HD + j], wt = W1[2 * HD + j];
        f[0] = fmaf(wx, xs, fmaf(wy, ys, fmaf(wt, ts, b1[j])));
        f[1] = wx; f[2] = wy; f[3] = wt;
        tanh_jet(f, ha);
        j = 2 * jp + 1;
        wx = W1[j]; wy = W1[HD + j]; wt = W1[2 * HD + j];
        f[0] = fmaf(wx, xs, fmaf(wy, ys, fmaf(wt, ts, b1[j])));
        f[1] = wx; f[2] = wy; f[3] = wt;
        tanh_jet(f, hb);
#pragma unroll
        for (int c = 0; c < NC; ++c)
            *(unsigned*)&Hl[(s * NC + c) * KSTR + 2 * jp] = pack_bf16_rne(ha[c], hb[c]);
    }
    __syncthreads();

    // ---- Layers 2,3: MFMA GEMM + in-place tanh ----
#pragma unroll 1
    for (int L = 0; L < 2; ++L) {
        // wave wv owns m-tile wv (rows j in [16wv,16wv+16)), all 9 n-tiles
        const unsigned short* WT = wsT + L * HD * KSTR;
        const int mrow = 16 * wv + (ln & 15);
        const int koff = (ln >> 4) * 8;
        bf16x8 Af[4];
#pragma unroll
        for (int ks = 0; ks < 4; ++ks)
            Af[ks] = *(const bf16x8*)&WT[mrow * KSTR + ks * 32 + koff];
        f32x4 acc[9];
#pragma unroll
        for (int nt = 0; nt < 9; ++nt) acc[nt] = (f32x4)0.0f;
#pragma unroll
        for (int ks = 0; ks < 4; ++ks) {
#pragma unroll
            for (int nt = 0; nt < 9; ++nt) {
                const bf16x8 Bf = *(const bf16x8*)&Hl[(nt * 16 + (ln & 15)) * KSTR + ks * 32 + koff];
                acc[nt] = __builtin_amdgcn_mfma_f32_16x16x32_bf16(Af[ks], Bf, acc[nt], 0, 0, 0);
            }
        }
        __syncthreads();
        // write back pre-activations f (bf16) in place: C[m=j][n=(s,c)] -> Hl[n][j]
#pragma unroll
        for (int nt = 0; nt < 9; ++nt) {
            const int n = nt * 16 + (ln & 15);
            const int m = 16 * wv + (ln >> 4) * 4;
            uint2 w;
            w.x = pack_bf16_rne(acc[nt].x, acc[nt].y);
            w.y = pack_bf16_rne(acc[nt].z, acc[nt].w);
            *(uint2*)&Hl[n * KSTR + m] = w;
        }
        __syncthreads();
        // tanh phase: unit (s, jp) reads its 18 f's, writes 18 h's (same addrs)
        {
            const float* bL = L ? b3 : b2;
            const int s  = tid >> 6;
            const int jp = tid & 63;
            float fa[NC], fb[NC], ha[NC], hb[NC];
#pragma unroll
            for (int c = 0; c < NC; ++c) {
                const unsigned q = *(const unsigned*)&Hl[(s * NC + c) * KSTR + 2 * jp];
                fa[c] = bf_lo(q);
                fb[c] = bf_hi(q);
            }
            fa[0] += bL[2 * jp];
            fb[0] += bL[2 * jp + 1];
            tanh_jet(fa, ha);
            tanh_jet(fb, hb);
#pragma unroll
            for (int c = 0; c < NC; ++c)
                *(unsigned*)&Hl[(s * NC + c) * KSTR + 2 * jp] = pack_bf16_rne(ha[c], hb[c]);
        }
        __syncthreads();
    }

    // ---- Layer 4: psi jet coefs = W4 . h3  (one thread per (s,c) row) ----
    if (tid < NCOLS) {
        float acc = 0.0f;
#pragma unroll
        for (int kk = 0; kk < 16; ++kk) {
            const uint4 q = *(const uint4*)&Hl[tid * KSTR + kk * 8];
            const int k = kk * 8;
            acc = fmaf(bf_lo(q.x), W4[k + 0], acc);
            acc = fmaf(bf_hi(q.x), W4[k + 1], acc);
            acc = fmaf(bf_lo(q.y), W4[k + 2], acc);
            acc = fmaf(bf_hi(q.y), W4[k + 3], acc);
            acc = fmaf(bf_lo(q.z), W4[k + 4], acc);
            acc = fmaf(bf_hi(q.z), W4[k + 5], acc);
            acc = fmaf(bf_lo(q.w), W4[k + 6], acc);
            acc = fmaf(bf_hi(q.w), W4[k + 7], acc);
        }
        psis[tid] = acc;
    }
    __syncthreads();

    if (tid < SB) {
        const float* p = &psis[tid * NC];
        const float nu = nu_p[0];
        const float u  = p[2];
        const float v  = -p[1];
        const float wx = -(6.0f * p[9]  + 2.0f * p[11]);
        const float wy = -(2.0f * p[10] + 6.0f * p[12]);
        const float wt = -(2.0f * p[13] + 2.0f * p[14]);
        const float lapw = -(24.0f * p[15] + 8.0f * p[16] + 24.0f * p[17]);
        const float nse  = wt + wx * u + wy * v - nu * lapw;
        const int gi = s0 + tid;
        out[2 * gi]         = u;
        out[2 * gi + 1]     = v;
        out[2 * NSAMP + gi] = nse;
    }
}

extern "C" void kernel_launch(void* const* d_in, const int* in_sizes, int n_in,
                              void* d_out, int out_size, void* d_ws, size_t ws_size,
                              hipStream_t stream) {
    const float* x  = (const float*)d_in[0];
    const float* W1 = (const float*)d_in[1];
    const float* b1 = (const float*)d_in[2];
    const float* W2 = (const float*)d_in[3];
    const float* b2 = (const float*)d_in[4];
    const float* W3 = (const float*)d_in[5];
    const float* b3 = (const float*)d_in[6];
    const float* W4 = (const float*)d_in[7];
    const float* nu = (const float*)d_in[9];
    float* out = (float*)d_out;

    unsigned* wsT = (unsigned*)d_ws;   // 2 x 128 x 136 bf16 = 69632 B
    {
        const int total = 2 * HD * (KSTR / 2);
        hipLaunchKernelGGL(transpose_w, dim3((total + 255) / 256), dim3(256), 0, stream,
                           W2, W3, wsT);
    }
    hipLaunchKernelGGL(hydro_main, dim3(NSAMP / SB), dim3(512), 0, stream,
                       x, W1, b1, b2, b3, W4, nu,
                       (const unsigned short*)d_ws, out);
}

// Round 4
// 100.774 us; speedup vs baseline: 2.5327x; 1.0590x over previous
//
#include <hip/hip_runtime.h>
#include <hip/hip_bf16.h>

#define NSAMP 8192
#define HD 128
#define NC 18
#define SB 8            // samples per block
#define NCOLS 144       // SB*NC
#define KSTR 136        // padded k-stride in shorts (272B rows, 16B-aligned)

typedef __attribute__((ext_vector_type(8))) short bf16x8;
typedef __attribute__((ext_vector_type(4))) float f32x4;
typedef float f2 __attribute__((ext_vector_type(2)));

// Monomial map: 0:1 1:a 2:b 3:c 4:a2 5:ab 6:b2 7:ca 8:cb 9:a3 10:a2b 11:ab2
// 12:b3 13:ca2 14:cb2 15:a4 16:a2b2 17:b4   (a=dx, b=dy, c=dt)

__device__ __forceinline__ unsigned packf2(f2 v) {
    // v_cvt_pk_bf16_f32 on gfx950 (RNE), x -> low short, y -> high short
    __hip_bfloat162 h = __float22bfloat162_rn(float2{v.x, v.y});
    return *(unsigned*)&h;
}
__device__ __forceinline__ f2 unpk(unsigned r) {
    f2 v;
    v.x = __uint_as_float(r << 16);
    v.y = __uint_as_float(r & 0xffff0000u);
    return v;
}

// ---- float2-vectorized jet algebra (each thread carries 2 hidden units) ----
__device__ __forceinline__ void jmul2(const f2* __restrict__ p,
                                      const f2* __restrict__ q,
                                      f2* __restrict__ r) {
    r[0]  = p[0]*q[0];
    r[1]  = p[0]*q[1]  + p[1]*q[0];
    r[2]  = p[0]*q[2]  + p[2]*q[0];
    r[3]  = p[0]*q[3]  + p[3]*q[0];
    r[4]  = p[0]*q[4]  + p[4]*q[0]  + p[1]*q[1];
    r[5]  = p[0]*q[5]  + p[5]*q[0]  + p[1]*q[2]  + p[2]*q[1];
    r[6]  = p[0]*q[6]  + p[6]*q[0]  + p[2]*q[2];
    r[7]  = p[0]*q[7]  + p[7]*q[0]  + p[1]*q[3]  + p[3]*q[1];
    r[8]  = p[0]*q[8]  + p[8]*q[0]  + p[2]*q[3]  + p[3]*q[2];
    r[9]  = p[0]*q[9]  + p[9]*q[0]  + p[1]*q[4]  + p[4]*q[1];
    r[10] = p[0]*q[10] + p[10]*q[0] + p[1]*q[5]  + p[5]*q[1] + p[2]*q[4] + p[4]*q[2];
    r[11] = p[0]*q[11] + p[11]*q[0] + p[1]*q[6]  + p[6]*q[1] + p[2]*q[5] + p[5]*q[2];
    r[12] = p[0]*q[12] + p[12]*q[0] + p[2]*q[6]  + p[6]*q[2];
    r[13] = p[0]*q[13] + p[13]*q[0] + p[1]*q[7]  + p[7]*q[1] + p[3]*q[4] + p[4]*q[3];
    r[14] = p[0]*q[14] + p[14]*q[0] + p[2]*q[8]  + p[8]*q[2] + p[3]*q[6] + p[6]*q[3];
    r[15] = p[0]*q[15] + p[15]*q[0] + p[1]*q[9]  + p[9]*q[1] + p[4]*q[4];
    r[16] = p[0]*q[16] + p[16]*q[0] + p[1]*q[11] + p[11]*q[1] + p[2]*q[10] + p[10]*q[2]
          + p[4]*q[6]  + p[6]*q[4]  + p[5]*q[5];
    r[17] = p[0]*q[17] + p[17]*q[0] + p[2]*q[12] + p[12]*q[2] + p[6]*q[6];
}

__device__ __forceinline__ void tanh_jet2(const f2* __restrict__ f,
                                          f2* __restrict__ out) {
    f2 y;  y.x = tanhf(f[0].x);  y.y = tanhf(f[0].y);
    const f2 one = {1.0f, 1.0f};
    const f2 s  = one - y*y;
    const f2 t2 = -y*s;
    const f2 t3 = s*(y*y - 0.3333333333333333f);
    const f2 t4 = y*s*(one + one - 3.0f*y*y) * 0.3333333333333333f;
    f2 p[NC], A[NC], B[NC];
    p[0] = (f2)0.0f;
#pragma unroll
    for (int i = 1; i < NC; ++i) p[i] = f[i];
    A[0] = t3;
#pragma unroll
    for (int i = 1; i < NC; ++i) A[i] = t4 * p[i];
    jmul2(p, A, B);  B[0] += t2;
    jmul2(p, B, A);  A[0] += s;
    jmul2(p, A, out); out[0] += y;
}

__global__ __launch_bounds__(512, 4)
void hydro_main(const float* __restrict__ x,
                const float* __restrict__ W1, const float* __restrict__ b1,
                const float* __restrict__ W2, const float* __restrict__ b2,
                const float* __restrict__ W3, const float* __restrict__ b3,
                const float* __restrict__ W4, const float* __restrict__ nu_p,
                float* __restrict__ out) {
    __shared__ __align__(16) unsigned short Hl[NCOLS * KSTR];  // jets/preacts, bf16
    __shared__ float psis[NCOLS];

    const int tid = threadIdx.x;
    const int wv  = tid >> 6;
    const int ln  = tid & 63;
    const int s0  = blockIdx.x * SB;
    const int s   = tid >> 6;          // sample slot 0..7
    const int jp  = tid & 63;          // unit pair 0..63

    // ---- Layer 1: 512 unit-pairs, float2 jets ----
    {
        const float xs = x[3 * (s0 + s) + 0];
        const float ys = x[3 * (s0 + s) + 1];
        const float ts = x[3 * (s0 + s) + 2];
        const int j0 = 2 * jp;
        const f2 wx = *(const f2*)&W1[j0];
        const f2 wy = *(const f2*)&W1[HD + j0];
        const f2 wt = *(const f2*)&W1[2 * HD + j0];
        const f2 bb = *(const f2*)&b1[j0];
        f2 f[NC], h[NC];
#pragma unroll
        for (int c = 0; c < NC; ++c) f[c] = (f2)0.0f;
        f[0] = wx * xs + wy * ys + wt * ts + bb;
        f[1] = wx; f[2] = wy; f[3] = wt;
        tanh_jet2(f, h);
#pragma unroll
        for (int c = 0; c < NC; ++c)
            *(unsigned*)&Hl[(s * NC + c) * KSTR + j0] = packf2(h[c]);
    }
    __syncthreads();

    // ---- Layers 2,3: MFMA GEMM (A direct from fp32 W) + in-place tanh ----
#pragma unroll 1
    for (int L = 0; L < 2; ++L) {
        const float* __restrict__ W = L ? W3 : W2;
        // A-frag: lane holds A[m=j][k] for j = 16wv+(ln&15), k = ks*32+koff+0..7
        const int jj   = 16 * wv + (ln & 15);
        const int koff = (ln >> 4) * 8;
        bf16x8 Af[4];
#pragma unroll
        for (int ks = 0; ks < 4; ++ks) {
            union { uint4 u; bf16x8 v; } cv;
            const int kb = ks * 32 + koff;
            cv.u.x = packf2(f2{W[(kb + 0) * HD + jj], W[(kb + 1) * HD + jj]});
            cv.u.y = packf2(f2{W[(kb + 2) * HD + jj], W[(kb + 3) * HD + jj]});
            cv.u.z = packf2(f2{W[(kb + 4) * HD + jj], W[(kb + 5) * HD + jj]});
            cv.u.w = packf2(f2{W[(kb + 6) * HD + jj], W[(kb + 7) * HD + jj]});
            Af[ks] = cv.v;
        }
        f32x4 acc[9];
#pragma unroll
        for (int nt = 0; nt < 9; ++nt) acc[nt] = (f32x4)0.0f;
#pragma unroll
        for (int ks = 0; ks < 4; ++ks) {
#pragma unroll
            for (int nt = 0; nt < 9; ++nt) {
                const bf16x8 Bf = *(const bf16x8*)&Hl[(nt * 16 + (ln & 15)) * KSTR + ks * 32 + koff];
                acc[nt] = __builtin_amdgcn_mfma_f32_16x16x32_bf16(Af[ks], Bf, acc[nt], 0, 0, 0);
            }
        }
        __syncthreads();
        // write back pre-activations f (bf16): C[m=j][n=(s,c)] -> Hl[n][j]
#pragma unroll
        for (int nt = 0; nt < 9; ++nt) {
            const int n = nt * 16 + (ln & 15);
            const int m = 16 * wv + (ln >> 4) * 4;
            uint2 w;
            w.x = packf2(f2{acc[nt].x, acc[nt].y});
            w.y = packf2(f2{acc[nt].z, acc[nt].w});
            *(uint2*)&Hl[n * KSTR + m] = w;
        }
        __syncthreads();
        // tanh phase: unit-pair (s, jp), float2 jets, in-place
        {
            const float* bL = L ? b3 : b2;
            const int j0 = 2 * jp;
            f2 fa[NC], ha[NC];
#pragma unroll
            for (int c = 0; c < NC; ++c)
                fa[c] = unpk(*(const unsigned*)&Hl[(s * NC + c) * KSTR + j0]);
            fa[0] += *(const f2*)&bL[j0];
            tanh_jet2(fa, ha);
#pragma unroll
            for (int c = 0; c < NC; ++c)
                *(unsigned*)&Hl[(s * NC + c) * KSTR + j0] = packf2(ha[c]);
        }
        __syncthreads();
    }

    // ---- Layer 4: psi jet coefs = W4 . h3 ----
    if (tid < NCOLS) {
        float acc = 0.0f;
#pragma unroll
        for (int kk = 0; kk < 16; ++kk) {
            const uint4 q = *(const uint4*)&Hl[tid * KSTR + kk * 8];
            const int k = kk * 8;
            const f2 e0 = unpk(q.x), e1 = unpk(q.y), e2 = unpk(q.z), e3 = unpk(q.w);
            acc = fmaf(e0.x, W4[k + 0], acc);
            acc = fmaf(e0.y, W4[k + 1], acc);
            acc = fmaf(e1.x, W4[k + 2], acc);
            acc = fmaf(e1.y, W4[k + 3], acc);
            acc = fmaf(e2.x, W4[k + 4], acc);
            acc = fmaf(e2.y, W4[k + 5], acc);
            acc = fmaf(e3.x, W4[k + 6], acc);
            acc = fmaf(e3.y, W4[k + 7], acc);
        }
        psis[tid] = acc;
    }
    __syncthreads();

    if (tid < SB) {
        const float* p = &psis[tid * NC];
        const float nu = nu_p[0];
        const float u  = p[2];
        const float v  = -p[1];
        const float wx = -(6.0f * p[9]  + 2.0f * p[11]);
        const float wy = -(2.0f * p[10] + 6.0f * p[12]);
        const float wt = -(2.0f * p[13] + 2.0f * p[14]);
        const float lapw = -(24.0f * p[15] + 8.0f * p[16] + 24.0f * p[17]);
        const float nse  = wt + wx * u + wy * v - nu * lapw;
        const int gi = s0 + tid;
        out[2 * gi]         = u;
        out[2 * gi + 1]     = v;
        out[2 * NSAMP + gi] = nse;
    }
}

extern "C" void kernel_launch(void* const* d_in, const int* in_sizes, int n_in,
                              void* d_out, int out_size, void* d_ws, size_t ws_size,
                              hipStream_t stream) {
    const float* x  = (const float*)d_in[0];
    const float* W1 = (const float*)d_in[1];
    const float* b1 = (const float*)d_in[2];
    const float* W2 = (const float*)d_in[3];
    const float* b2 = (const float*)d_in[4];
    const float* W3 = (const float*)d_in[5];
    const float* b3 = (const float*)d_in[6];
    const float* W4 = (const float*)d_in[7];
    const float* nu = (const float*)d_in[9];
    float* out = (float*)d_out;

    hipLaunchKernelGGL(hydro_main, dim3(NSAMP / SB), dim3(512), 0, stream,
                       x, W1, b1, W2, b2, W3, b3, W4, nu, out);
}